// Round 1
// 1193.018 us; speedup vs baseline: 1.1969x; 1.1969x over previous
//
#include <hip/hip_runtime.h>
#include <math.h>

#define L 2048
#define D 64
#define MT 32        // query rows per block
#define KT 128       // keys per tile
#define NT 256       // threads (4 waves)

typedef short bf16x8 __attribute__((ext_vector_type(8)));
typedef short bf16x4 __attribute__((ext_vector_type(4)));
typedef float f32x4  __attribute__((ext_vector_type(4)));

#define MFMA16 __builtin_amdgcn_mfma_f32_16x16x32_bf16

__device__ __forceinline__ short f2bf(float f) {
    union { float f; unsigned u; } x; x.f = f;
    unsigned r = x.u + 0x7fffu + ((x.u >> 16) & 1u);  // RNE
    return (short)(r >> 16);
}

// ---------- prekernel 1: fp32 rows -> bf16, 16B chunks XOR-swizzled by row ----
// dst row layout: chunk c (8 bf16) stored at position c ^ (row & 7).
__global__ __launch_bounds__(NT) void conv_swz(
    const float* __restrict__ src, short* __restrict__ dst, int nrows)
{
    int g = blockIdx.x * NT + threadIdx.x;     // one 16B output chunk
    if (g >= nrows * 8) return;
    int row = g >> 3, c = g & 7;
    const float4* s4 = (const float4*)(src + (size_t)row * D + c * 8);
    float4 a = s4[0], b = s4[1];
    bf16x8 t;
    t[0]=f2bf(a.x); t[1]=f2bf(a.y); t[2]=f2bf(a.z); t[3]=f2bf(a.w);
    t[4]=f2bf(b.x); t[5]=f2bf(b.y); t[6]=f2bf(b.z); t[7]=f2bf(b.w);
    *(bf16x8*)(dst + (size_t)row * D + ((c ^ (row & 7)) * 8)) = t;
}

// ---------- prekernel 2: V -> Vt tiles [head][kt][d][key] bf16, swizzled ----
__global__ __launch_bounds__(NT) void vtrans(
    const float* __restrict__ v, short* __restrict__ vt)
{
    const int h  = blockIdx.x >> 4;
    const int kt = blockIdx.x & 15;
    const float* src = v + ((size_t)h * L + (size_t)kt * KT) * D;
    short* dst = vt + (size_t)blockIdx.x * (D * KT);
    __shared__ short Vs[KT * 68];              // [key][d], pad to 68 (8B-aligned)
    const int t = threadIdx.x;
    {
        const int r = t & 127, seg = t >> 7;   // 32 floats each
        const float4* s4 = (const float4*)(src + r * D + seg * 32);
        #pragma unroll
        for (int kq = 0; kq < 8; ++kq) {
            float4 a = s4[kq];
            bf16x4 b;
            b[0]=f2bf(a.x); b[1]=f2bf(a.y); b[2]=f2bf(a.z); b[3]=f2bf(a.w);
            *(bf16x4*)(Vs + r * 68 + seg * 32 + kq * 4) = b;
        }
    }
    __syncthreads();
    #pragma unroll
    for (int j = 0; j < 4; ++j) {
        const int cg = t + NT * j;             // 1024 chunks total
        const int d = cg >> 4, c = cg & 15;    // row d (256B), chunk c
        bf16x8 o;
        #pragma unroll
        for (int jj = 0; jj < 8; ++jj) o[jj] = Vs[(c * 8 + jj) * 68 + d];
        *(bf16x8*)(dst + d * KT + ((c ^ (d & 7)) * 8)) = o;
    }
}

// ---------- main: single pass, deferred normalization ----
// S^T = K·Q^T via MFMA (A=K frag, B=Q frag) so C[key][q]: lane holds
// 4 consecutive keys -> int4 mask loads, float4 attn stores, b64 Ps writes.
// Writes UNNORMALIZED e to attn; row sums -> invs; O scaled in epilogue.
__global__ __launch_bounds__(NT, 4) void sdpa_fused(
    const short* __restrict__ qb,
    const short* __restrict__ kb,
    const short* __restrict__ vtb,
    const int*   __restrict__ mask,
    float* __restrict__ out,
    float* __restrict__ attn,
    float* __restrict__ invs)
{
    const int bid  = blockIdx.x;      // 2048
    const int bn   = bid >> 6;        // head 0..31
    const int qt   = bid & 63;
    const int row0 = qt * MT;
    const int tid  = threadIdx.x;
    const int wave = tid >> 6;
    const int lane = tid & 63;
    const int lq   = lane & 15;
    const int lg   = lane >> 4;
    const int swz  = lq & 7;          // chunk XOR for all swizzled LDS reads

    __shared__ __align__(16) char smem[40960];   // 4 blocks/CU exactly
    short* Kb = (short*)smem;                    // 128x64 bf16 (16KB)
    short* Vb = (short*)(smem + 16384);          // 64x128 bf16 (16KB)
    short* Ps = (short*)(smem + 32768);          // 32x128 bf16 (8KB)
    short* Qt = Ps;                              // prologue alias (4KB)
    float* sums_w = (float*)(smem + 32768);      // [4][32] post-loop alias
    float* inv_l  = (float*)(smem + 32768 + 512);

    const short* qh = qb  + (size_t)bn * L * D;
    const short* kh = kb  + (size_t)bn * L * D;
    const int*   mg = mask + ((size_t)bn * L + row0) * L;
    float*       ag = attn + ((size_t)bn * L + row0) * L;

    // ---- persistent Q fragments (B operand: lane lq = q col) ----
    *(bf16x8*)(Qt + tid * 8) = *(const bf16x8*)(qh + (size_t)row0 * D + tid * 8);
    __syncthreads();
    bf16x8 qf[2][2];
    #pragma unroll
    for (int qq = 0; qq < 2; ++qq)
        #pragma unroll
        for (int s = 0; s < 2; ++s)
            qf[qq][s] = *(const bf16x8*)(Qt + (qq*16 + lq) * D + (((s*4 + lg) ^ swz) * 8));
    __syncthreads();

    f32x4 of[2] = {};                 // O[q=r*16+lg*4+i][d=wave*16+lq]
    float sumreg[2] = {0.f, 0.f};     // row sums for q = qq*16+lq

    for (int kt = 0; kt < L / KT; ++kt) {
        const int kb0 = kt * KT;
        // issue-early: K/V tiles + mask into regs (consumed after barriers)
        const short* ks = kh + (size_t)kb0 * D;
        const short* vs = vtb + ((size_t)bn * (L / KT) + kt) * (D * KT);
        bf16x8 kr[4], vr[4];
        #pragma unroll
        for (int c = 0; c < 4; ++c) {
            kr[c] = *(const bf16x8*)(ks + (c * NT + tid) * 8);
            vr[c] = *(const bf16x8*)(vs + (c * NT + tid) * 8);
        }
        int4 m4[2][2];
        #pragma unroll
        for (int kk = 0; kk < 2; ++kk)
            #pragma unroll
            for (int qq = 0; qq < 2; ++qq)
                m4[kk][qq] = *(const int4*)(mg + (size_t)(qq*16 + lq) * L
                                               + kb0 + wave*32 + kk*16 + lg*4);
        __syncthreads();              // B0: prev tile's LDS readers done
        #pragma unroll
        for (int c = 0; c < 4; ++c) {
            *(bf16x8*)(Kb + (c * NT + tid) * 8) = kr[c];
            *(bf16x8*)(Vb + (c * NT + tid) * 8) = vr[c];
        }
        __syncthreads();              // B1: tiles staged

        // S^T tile: wave owns keys [wave*32, wave*32+32)
        f32x4 acc[2][2] = {};         // [kk][qq]; row=key(lg*4+i), col=q(lq)
        __builtin_amdgcn_s_setprio(1);
        #pragma unroll
        for (int s = 0; s < 2; ++s) {
            bf16x8 a0 = *(const bf16x8*)(Kb + (wave*32 + lq)      * D + (((s*4 + lg) ^ swz) * 8));
            bf16x8 a1 = *(const bf16x8*)(Kb + (wave*32 + 16 + lq) * D + (((s*4 + lg) ^ swz) * 8));
            acc[0][0] = MFMA16(a0, qf[0][s], acc[0][0], 0, 0, 0);
            acc[0][1] = MFMA16(a0, qf[1][s], acc[0][1], 0, 0, 0);
            acc[1][0] = MFMA16(a1, qf[0][s], acc[1][0], 0, 0, 0);
            acc[1][1] = MFMA16(a1, qf[1][s], acc[1][1], 0, 0, 0);
        }
        __builtin_amdgcn_s_setprio(0);

        // mask -> e = exp(S/8): attn (unnormalized fp32), Ps (bf16), row sums
        #pragma unroll
        for (int kk = 0; kk < 2; ++kk)
            #pragma unroll
            for (int qq = 0; qq < 2; ++qq) {
                const int qrow = qq*16 + lq;
                const int colL = wave*32 + kk*16 + lg*4;
                const int4 m = m4[kk][qq];
                const f32x4 a = acc[kk][qq];
                const float e0 = m.x ? 0.f : __expf(a[0] * 0.125f);
                const float e1 = m.y ? 0.f : __expf(a[1] * 0.125f);
                const float e2 = m.z ? 0.f : __expf(a[2] * 0.125f);
                const float e3 = m.w ? 0.f : __expf(a[3] * 0.125f);
                sumreg[qq] += (e0 + e1) + (e2 + e3);
                float4 ev; ev.x = e0; ev.y = e1; ev.z = e2; ev.w = e3;
                *(float4*)(ag + (size_t)qrow * L + kb0 + colL) = ev;
                bf16x4 pb;
                pb[0]=f2bf(e0); pb[1]=f2bf(e1); pb[2]=f2bf(e2); pb[3]=f2bf(e3);
                *(bf16x4*)(Ps + qrow * KT + (colL ^ (swz * 8))) = pb;
            }
        __syncthreads();              // B2: Ps complete (all waves)

        // O += Ps @ Vt ; wave owns d cols [wave*16, wave*16+16)
        __builtin_amdgcn_s_setprio(1);
        #pragma unroll
        for (int s2 = 0; s2 < 4; ++s2) {
            const int ch = ((s2*4 + lg) ^ swz) * 8;
            bf16x8 vb = *(const bf16x8*)(Vb + (wave*16 + lq) * KT + ch);
            bf16x8 p0 = *(const bf16x8*)(Ps + lq * KT + ch);
            bf16x8 p1 = *(const bf16x8*)(Ps + (16 + lq) * KT + ch);
            of[0] = MFMA16(p0, vb, of[0], 0, 0, 0);
            of[1] = MFMA16(p1, vb, of[1], 0, 0, 0);
        }
        __builtin_amdgcn_s_setprio(0);
    }

    // ---- finalize: row sums -> inv, write invs + scaled O ----
    #pragma unroll
    for (int qq = 0; qq < 2; ++qq) {
        sumreg[qq] += __shfl_xor(sumreg[qq], 16, 64);  // reduce across lg
        sumreg[qq] += __shfl_xor(sumreg[qq], 32, 64);
    }
    __syncthreads();                  // last PV reads of Ps done
    if (lane < 16) {
        sums_w[wave * 32 + lq]      = sumreg[0];
        sums_w[wave * 32 + 16 + lq] = sumreg[1];
    }
    __syncthreads();
    if (tid < MT) {
        const float s = sums_w[tid] + sums_w[32 + tid] + sums_w[64 + tid] + sums_w[96 + tid];
        const float inv = 1.0f / s;
        inv_l[tid] = inv;
        invs[(size_t)bn * L + row0 + tid] = inv;
    }
    __syncthreads();
    #pragma unroll
    for (int r = 0; r < 2; ++r)
        #pragma unroll
        for (int i = 0; i < 4; ++i) {
            const int qrow = r*16 + lg*4 + i;
            out[((size_t)bn * L + row0 + qrow) * D + wave*16 + lq] = of[r][i] * inv_l[qrow];
        }
}

// ---------- postkernel: attn *= inv_sum[row] (pure streaming) ----
__global__ __launch_bounds__(NT) void scale_attn(
    float* __restrict__ attn, const float* __restrict__ invs, long long total4)
{
    long long i = (long long)blockIdx.x * NT + threadIdx.x;
    const long long stride = (long long)gridDim.x * NT;
    float4* a4 = (float4*)attn;
    for (; i < total4; i += stride) {
        const float inv = invs[i >> 9];       // 512 float4 per row
        float4 t = a4[i];
        t.x *= inv; t.y *= inv; t.z *= inv; t.w *= inv;
        a4[i] = t;
    }
}

extern "C" void kernel_launch(void* const* d_in, const int* in_sizes, int n_in,
                              void* d_out, int out_size, void* d_ws, size_t ws_size,
                              hipStream_t stream) {
    const float* q    = (const float*)d_in[0];
    const float* k    = (const float*)d_in[1];
    const float* v    = (const float*)d_in[2];
    const int*   mask = (const int*)d_in[3];

    float* out = (float*)d_out;
    const int rows = in_sizes[0] / D;          // B*N*L = 65536
    float* attn = out + (size_t)rows * D;      // outputs concatenated flat

    // workspace layout: qb | kb | vtb (bf16) | invs (fp32)  ~25.4 MB
    short* qb   = (short*)d_ws;
    short* kb   = qb  + (size_t)rows * D;
    short* vtb  = kb  + (size_t)rows * D;
    float* invs = (float*)(vtb + (size_t)rows * D);

    const int heads = rows / L;                // 32
    conv_swz<<<rows * 8 / NT, NT, 0, stream>>>(q, qb, rows);
    conv_swz<<<rows * 8 / NT, NT, 0, stream>>>(k, kb, rows);
    vtrans<<<heads * (L / KT), NT, 0, stream>>>(v, vtb);
    sdpa_fused<<<rows / MT, NT, 0, stream>>>(qb, kb, vtb, mask, out, attn, invs);
    scale_attn<<<8192, NT, 0, stream>>>(attn, invs, (long long)rows * (L / 4));
}